// Round 16
// baseline (383.663 us; speedup 1.0000x reference)
//
#include <hip/hip_runtime.h>
#include <hip/hip_bf16.h>

typedef __attribute__((ext_vector_type(4))) float f32x4;
typedef __attribute__((ext_vector_type(2))) long i64x2;

typedef const __attribute__((address_space(1))) void* gptr_t;
typedef __attribute__((address_space(3))) void* lptr_t;

#define NROW 8192
#define DDIM 256
#define HALF_B 4096
#define NB 64                        // 8192/128 tile bands
#define NTILES (NB * (NB + 1) / 2)   // 2080 upper-triangle tiles
#define GRID 512                     // 2 blocks/CU exactly (LDS-bounded)

// exp(dot/T) = exp2(dot * log2(e)/T), T = 0.07
#define E2SCALE 20.6099291555566196f
#define INV_T   14.2857142857142858f

__device__ __forceinline__ float fast_exp2(float x) {
  float r;
  asm("v_exp_f32 %0, %1" : "=v"(r) : "v"(x));
  return r;
}

// grid-wide sync: all blocks resident by construction (GRID = 2 x 256 CU,
// LDS 66.5KB -> exactly 2 blocks/CU, launch_bounds caps regs).
__device__ __forceinline__ void gridsync(unsigned int* ctr) {
  __threadfence();            // flush this thread's writes (device scope)
  __syncthreads();            // all block threads' fences done
  if (threadIdx.x == 0) {
    __hip_atomic_fetch_add(ctr, 1u, __ATOMIC_ACQ_REL, __HIP_MEMORY_SCOPE_AGENT);
    while (__hip_atomic_load(ctr, __ATOMIC_ACQUIRE, __HIP_MEMORY_SCOPE_AGENT)
           < GRID) {
      __builtin_amdgcn_s_sleep(8);
    }
  }
  __syncthreads();
  __threadfence();            // acquire: discard stale local views
}

// ---------------- fused kernel: normalize -> Gram tiles -> loss -------------
// Phase N: 16 rows/block normalize + fp8(e4m3) quant, paired swizzled layout
//   (R10-validated): byte = row*256 + (p>>1)*128 + ((((p&1)<<2)|g)^(row&7))*16
//   + e*8 + o, so half-K staging is linear and ds_read_b128 is conflict-free.
// Phase G: R14-validated per-tile body: full-K stage, vmcnt(4)/vmcnt(0)
//   counted halves, 64 fp8 MFMAs, scatter-store epilogue -> P, pos.
// Phase R: 16 rows/block: sum 64 P-partials, log - pos, atomicAdd -> lacc;
//   last block at ctrC finalizes out[0].
__global__ __launch_bounds__(512, 4) void fused_kernel(
    const float* __restrict__ z_i, const float* __restrict__ z_j,
    unsigned char* __restrict__ zn, float* __restrict__ P,
    float* __restrict__ pos, float* __restrict__ lacc,
    unsigned int* __restrict__ ctrs, float* __restrict__ out) {
  __shared__ char smem[66560];   // A0@0 A1@16K B0@32K B1@48K | red@65536
  float (*rowmat)[68] = (float (*)[68])smem;            // 34816 B @0 (aliased)
  float (*colmat)[16] = (float (*)[16])(smem + 34816);  // 8192 B (aliased)
  float* red = (float*)(smem + 65536);

  const int tid = threadIdx.x;
  const int lane = tid & 63;
  const int wid = tid >> 6;          // 0..7
  const int wr = wid >> 2;           // 0..1 (64 rows each)
  const int wc = wid & 3;            // 0..3 (32 cols each)
  const int bid = blockIdx.x;

  // ================= Phase N: normalize 16 rows =================
  {
    const int g  = (lane >> 1) & 3;
    const int e  = (lane >> 3) & 1;
    const int ph = (lane >> 4) & 1;
    const int pq = lane >> 5;
    const int o  = (lane & 1) * 4;
    const int cbase = (ph << 2) | g;
#pragma unroll
    for (int rr = 0; rr < 2; ++rr) {
      const int row = bid * 16 + wid * 2 + rr;
      const float* src = (row < HALF_B) ? (z_i + (size_t)row * DDIM)
                                        : (z_j + (size_t)(row - HALF_B) * DDIM);
      float4 v = *reinterpret_cast<const float4*>(src + lane * 4);
      float ss = v.x * v.x + v.y * v.y + v.z * v.z + v.w * v.w;
#pragma unroll
      for (int m = 32; m; m >>= 1) ss += __shfl_xor(ss, m);
      const float inv = 1.0f / sqrtf(ss);
      int pk = __builtin_amdgcn_cvt_pk_fp8_f32(v.x * inv, v.y * inv, 0, false);
      pk = __builtin_amdgcn_cvt_pk_fp8_f32(v.z * inv, v.w * inv, pk, true);
      const int pp = pq * 128 + ((cbase ^ (row & 7)) << 4) + e * 8 + o;
      *reinterpret_cast<unsigned int*>(zn + (size_t)row * DDIM + pp) =
          (unsigned int)pk;
    }
  }
  gridsync(&ctrs[0]);

  // ================= Phase G: Gram tiles =================
  const int rloc = tid >> 3;
  const int c16 = (tid & 7) * 16;
  const int r15 = lane & 15, g = lane >> 4, r7 = lane & 7;
  const int abase = (wr * 64 + r15) * 128;
  const int bbase = (wc * 32 + r15) * 128;

  for (int tile = bid; tile < NTILES; tile += GRID) {
    int p = tile;
    int by = 0;
    while (p >= NB - by) { p -= NB - by; ++by; }
    const int bx = by + p;
    const int rowBase = by * 128;
    const int colBase = bx * 128;
    const bool isdiag = (bx == by);
    const bool ispos = (bx - by == 32);

    // ---- stage full-K (half0's 4 loads first)
#pragma unroll
    for (int h = 0; h < 2; ++h) {
#pragma unroll
      for (int t = 0; t < 2; ++t) {
        const int r = t * 64 + rloc;
        const unsigned char* ga =
            zn + (size_t)(rowBase + r) * DDIM + h * 128 + c16;
        const unsigned char* gb =
            zn + (size_t)(colBase + r) * DDIM + h * 128 + c16;
        __builtin_amdgcn_global_load_lds((gptr_t)ga,
            (lptr_t)(smem + h * 16384 + t * 8192 + wid * 1024), 16, 0, 0);
        __builtin_amdgcn_global_load_lds((gptr_t)gb,
            (lptr_t)(smem + 32768 + h * 16384 + t * 8192 + wid * 1024),
            16, 0, 0);
      }
    }

    f32x4 acc[4][2] = {};
    asm volatile("s_waitcnt vmcnt(4)" ::: "memory");
    __builtin_amdgcn_s_barrier();
    __builtin_amdgcn_sched_barrier(0);

#pragma unroll
    for (int h = 0; h < 2; ++h) {
      if (h == 1) {
        asm volatile("s_waitcnt vmcnt(0)" ::: "memory");
        __builtin_amdgcn_s_barrier();
        __builtin_amdgcn_sched_barrier(0);
      }
      const char* Ab = reinterpret_cast<const char*>(smem) + h * 16384;
      const char* Bb = reinterpret_cast<const char*>(smem) + 32768 + h * 16384;
#pragma unroll
      for (int lp = 0; lp < 2; ++lp) {
        const int off = ((((lp << 2) | g) ^ r7) << 4);
        i64x2 A0 = *reinterpret_cast<const i64x2*>(Ab + abase + off);
        i64x2 A1 = *reinterpret_cast<const i64x2*>(Ab + abase + 2048 + off);
        i64x2 A2 = *reinterpret_cast<const i64x2*>(Ab + abase + 4096 + off);
        i64x2 A3 = *reinterpret_cast<const i64x2*>(Ab + abase + 6144 + off);
        i64x2 B0 = *reinterpret_cast<const i64x2*>(Bb + bbase + off);
        i64x2 B1 = *reinterpret_cast<const i64x2*>(Bb + bbase + 2048 + off);
#pragma unroll
        for (int e = 0; e < 2; ++e) {
          const long a0 = A0[e], a1 = A1[e], a2 = A2[e], a3 = A3[e];
          const long b0 = B0[e], b1 = B1[e];
          acc[0][0] = __builtin_amdgcn_mfma_f32_16x16x32_fp8_fp8(a0, b0, acc[0][0], 0, 0, 0);
          acc[0][1] = __builtin_amdgcn_mfma_f32_16x16x32_fp8_fp8(a0, b1, acc[0][1], 0, 0, 0);
          acc[1][0] = __builtin_amdgcn_mfma_f32_16x16x32_fp8_fp8(a1, b0, acc[1][0], 0, 0, 0);
          acc[1][1] = __builtin_amdgcn_mfma_f32_16x16x32_fp8_fp8(a1, b1, acc[1][1], 0, 0, 0);
          acc[2][0] = __builtin_amdgcn_mfma_f32_16x16x32_fp8_fp8(a2, b0, acc[2][0], 0, 0, 0);
          acc[2][1] = __builtin_amdgcn_mfma_f32_16x16x32_fp8_fp8(a2, b1, acc[2][1], 0, 0, 0);
          acc[3][0] = __builtin_amdgcn_mfma_f32_16x16x32_fp8_fp8(a3, b0, acc[3][0], 0, 0, 0);
          acc[3][1] = __builtin_amdgcn_mfma_f32_16x16x32_fp8_fp8(a3, b1, acc[3][1], 0, 0, 0);
        }
      }
    }
    __syncthreads();   // A/B reads done; LDS becomes rowmat/colmat

    // ---- epilogue ph1: exp + scatter partials (R14-validated)
    float colpart[2] = {0.0f, 0.0f};
#pragma unroll
    for (int m = 0; m < 4; ++m) {
#pragma unroll
      for (int v = 0; v < 4; ++v) {
        const int lrow = wr * 64 + m * 16 + (lane >> 4) * 4 + v;
        const int gi = rowBase + lrow;
        float rp = 0.0f;
#pragma unroll
        for (int n = 0; n < 2; ++n) {
          const float d = acc[m][n][v];
          float val = fast_exp2(d * E2SCALE);
          if (isdiag) {
            const int gj = colBase + wc * 32 + n * 16 + r15;
            if (gi == gj) val = 0.0f;           // exclude diagonal
          } else if (ispos) {
            const int gj = colBase + wc * 32 + n * 16 + r15;
            if (gj == gi + HALF_B) {            // positive pair
              const float pv = d * INV_T;
              pos[gi] = pv;
              pos[gj] = pv;
            }
          }
          rp += val;
          colpart[n] += val;
        }
        rowmat[lrow][wc * 16 + r15] = rp;
      }
    }
    colmat[wc * 32 + r15][wr * 4 + (lane >> 4)] = colpart[0];
    colmat[wc * 32 + 16 + r15][wr * 4 + (lane >> 4)] = colpart[1];
    __syncthreads();

    // ---- epilogue ph2: read-reduce + coalesced P stores
    {
      const int row = tid >> 2;
      const int seg = tid & 3;
      const float* rr = &rowmat[row][seg * 16];
      f32x4 a0 = *reinterpret_cast<const f32x4*>(rr);
      f32x4 a1 = *reinterpret_cast<const f32x4*>(rr + 4);
      f32x4 a2 = *reinterpret_cast<const f32x4*>(rr + 8);
      f32x4 a3 = *reinterpret_cast<const f32x4*>(rr + 12);
      f32x4 t4 = (a0 + a1) + (a2 + a3);
      float s = (t4[0] + t4[1]) + (t4[2] + t4[3]);
      s += __shfl_xor(s, 1);
      s += __shfl_xor(s, 2);
      if (seg == 0) P[(size_t)bx * NROW + rowBase + row] = s;
    }
    if (tid < 128 && !isdiag) {
      const float* cc = colmat[tid];
      f32x4 c0 = *reinterpret_cast<const f32x4*>(cc);
      f32x4 c1 = *reinterpret_cast<const f32x4*>(cc + 4);
      f32x4 c2 = *reinterpret_cast<const f32x4*>(cc + 8);
      f32x4 c3 = *reinterpret_cast<const f32x4*>(cc + 12);
      f32x4 t4 = (c0 + c1) + (c2 + c3);
      P[(size_t)by * NROW + colBase + tid] =
          (t4[0] + t4[1]) + (t4[2] + t4[3]);
    }
    __syncthreads();   // protect rowmat/colmat before next tile's staging
  }
  gridsync(&ctrs[1]);

  // ================= Phase R: row reduce + loss =================
  {
    const int row = bid * 16 + (tid >> 5);   // 16 rows/block, 32 lanes/row
    const int kidx = tid & 31;
    float s = P[(size_t)kidx * NROW + row] +
              P[(size_t)(kidx + 32) * NROW + row];
    s += __shfl_xor(s, 16);
    s += __shfl_xor(s, 8);
    s += __shfl_xor(s, 4);
    s += __shfl_xor(s, 2);
    s += __shfl_xor(s, 1);
    if (kidx == 0) red[tid >> 5] = logf(s) - pos[row];
    __syncthreads();
    if (tid == 0) {
      float t = 0.0f;
#pragma unroll
      for (int i = 0; i < 16; ++i) t += red[i];
      atomicAdd(lacc, t);
      __threadfence();
      const unsigned done =
          __hip_atomic_fetch_add(&ctrs[2], 1u, __ATOMIC_ACQ_REL,
                                 __HIP_MEMORY_SCOPE_AGENT);
      if (done == (unsigned)(GRID - 1)) {
        const float v = atomicAdd(lacc, 0.0f);   // device-coherent read
        out[0] = v * (1.0f / (float)NROW);
      }
    }
  }
}

extern "C" void kernel_launch(void* const* d_in, const int* in_sizes, int n_in,
                              void* d_out, int out_size, void* d_ws, size_t ws_size,
                              hipStream_t stream) {
  const float* z_i = (const float*)d_in[0];
  const float* z_j = (const float*)d_in[1];
  float* out = (float*)d_out;

  char* ws = (char*)d_ws;
  unsigned char* zn = (unsigned char*)ws;                        // 2 MB fp8
  float* pos  = (float*)(ws + 2097152);                          // 32 KB
  float* P    = (float*)(ws + 2097152 + 32768);                  // 2 MB
  float* lacc = (float*)(ws + 2097152 + 32768 + 2097152);        // 4 B
  unsigned int* ctrs = (unsigned int*)(ws + 2097152 + 32768 + 2097152 + 4);

  hipMemsetAsync(lacc, 0, 16, stream);   // lacc + 3 counters
  fused_kernel<<<GRID, 512, 0, stream>>>(z_i, z_j, zn, P, pos, lacc, ctrs, out);
}

// Round 17
// 36.196 us; speedup vs baseline: 10.5997x; 10.5997x over previous
//
#include <hip/hip_runtime.h>
#include <hip/hip_bf16.h>

typedef __attribute__((ext_vector_type(4))) float f32x4;
typedef __attribute__((ext_vector_type(2))) long i64x2;

typedef const __attribute__((address_space(1))) void* gptr_t;
typedef __attribute__((address_space(3))) void* lptr_t;

#define NROW 8192
#define DDIM 256
#define HALF_B 4096
#define NB 64                        // 8192/128 tile bands
#define NTILES (NB * (NB + 1) / 2)   // 2080 upper-triangle tiles

// exp(dot/T) = exp2(dot * log2(e)/T), T = 0.07
#define E2SCALE 20.6099291555566196f
#define INV_T   14.2857142857142858f

__device__ __forceinline__ float fast_exp2(float x) {
  float r;
  asm("v_exp_f32 %0, %1" : "=v"(r) : "v"(x));
  return r;
}

// ---------------- kernel 1: normalize + fp8(e4m3) quant, paired layout -----
// (R10/R14-validated) byte = row*256 + (p>>1)*128 + ((((p&1)<<2)|g)^(row&7))*16
// + e*8 + o: half-K runs are linear for global_load_lds; ds_read conflict-free.
__global__ __launch_bounds__(256) void normalize_kernel(
    const float* __restrict__ z_i, const float* __restrict__ z_j,
    unsigned char* __restrict__ zn, float* __restrict__ lacc,
    unsigned int* __restrict__ counter) {
  const int lane = threadIdx.x & 63;
  const int w = blockIdx.x * 4 + (threadIdx.x >> 6);  // wave id 0..2047
  const int g  = (lane >> 1) & 3;
  const int e  = (lane >> 3) & 1;
  const int ph = (lane >> 4) & 1;
  const int pq = lane >> 5;
  const int o  = (lane & 1) * 4;
  const int cbase = (ph << 2) | g;
  for (int row = w; row < NROW; row += 2048) {
    const float* src = (row < HALF_B) ? (z_i + (size_t)row * DDIM)
                                      : (z_j + (size_t)(row - HALF_B) * DDIM);
    float4 v = *reinterpret_cast<const float4*>(src + lane * 4);
    float ss = v.x * v.x + v.y * v.y + v.z * v.z + v.w * v.w;
#pragma unroll
    for (int m = 32; m; m >>= 1) ss += __shfl_xor(ss, m);
    const float inv = 1.0f / sqrtf(ss);
    int pk = __builtin_amdgcn_cvt_pk_fp8_f32(v.x * inv, v.y * inv, 0, false);
    pk = __builtin_amdgcn_cvt_pk_fp8_f32(v.z * inv, v.w * inv, pk, true);
    const int pos = pq * 128 + ((cbase ^ (row & 7)) << 4) + e * 8 + o;
    *reinterpret_cast<unsigned int*>(zn + (size_t)row * DDIM + pos) =
        (unsigned int)pk;
  }
  if (blockIdx.x == 0 && threadIdx.x == 0) { *lacc = 0.0f; *counter = 0u; }
}

// ---------------- kernel 2: 128x128 Gram tiles, 256 thr, 4 blocks/CU --------
// 4 waves (2x2), wave-tile 64x64, acc[4][4]. Half-K staged into ONE 32KB
// buffer (A_h 16K @0, B_h 16K @16K) -> LDS 33KB -> 4 blocks/CU = 4-deep
// block-level latency overlap (vs R14's 2). ds_read algebra unchanged
// (proven conflict-free). Epilogue: R15-validated swizzled rowmat (aliases
// stage region) + colmat[128][2] @32768.
__global__ __launch_bounds__(256, 4) void gram_kernel(
    const unsigned char* __restrict__ zn,
    float* __restrict__ P, float* __restrict__ pos) {
  __shared__ char smem[33792];   // A@0 B@16384 | colmat @32768 (1KB)
  float (*colmat)[2] = (float (*)[2])(smem + 32768);

  const int tid = threadIdx.x;
  const int lane = tid & 63;
  const int wid = tid >> 6;          // 0..3
  const int wr = wid >> 1;           // 0..1 (64 rows)
  const int wc = wid & 1;            // 0..1 (64 cols)

  int p = blockIdx.x;
  int by = 0;
  while (p >= NB - by) { p -= NB - by; ++by; }
  const int bx = by + p;
  const int rowBase = by * 128;
  const int colBase = bx * 128;
  const bool isdiag = (bx == by);
  const bool ispos = (bx - by == 32);

  const int rloc = tid >> 3;         // 0..31
  const int c16 = (tid & 7) * 16;
  const int r15 = lane & 15, g = lane >> 4, r7 = lane & 7;
  const int abase = (wr * 64 + r15) * 128;
  const int bbase = (wc * 64 + r15) * 128;

  f32x4 acc[4][4] = {};

#pragma unroll
  for (int h = 0; h < 2; ++h) {
    // ---- stage half h: A rows then B rows (linear dest, swizzle in layout)
#pragma unroll
    for (int i = 0; i < 4; ++i) {
      const int r = i * 32 + rloc;
      const unsigned char* ga =
          zn + (size_t)(rowBase + r) * DDIM + h * 128 + c16;
      __builtin_amdgcn_global_load_lds((gptr_t)ga,
          (lptr_t)(smem + i * 4096 + wid * 1024), 16, 0, 0);
    }
#pragma unroll
    for (int i = 0; i < 4; ++i) {
      const int r = i * 32 + rloc;
      const unsigned char* gb =
          zn + (size_t)(colBase + r) * DDIM + h * 128 + c16;
      __builtin_amdgcn_global_load_lds((gptr_t)gb,
          (lptr_t)(smem + 16384 + i * 4096 + wid * 1024), 16, 0, 0);
    }
    asm volatile("s_waitcnt vmcnt(0)" ::: "memory");
    __builtin_amdgcn_s_barrier();
    __builtin_amdgcn_sched_barrier(0);

    const char* Ab = reinterpret_cast<const char*>(smem);
    const char* Bb = reinterpret_cast<const char*>(smem) + 16384;
#pragma unroll
    for (int lp = 0; lp < 2; ++lp) {
      const int off = ((((lp << 2) | g) ^ r7) << 4);
      i64x2 A0 = *reinterpret_cast<const i64x2*>(Ab + abase + off);
      i64x2 A1 = *reinterpret_cast<const i64x2*>(Ab + abase + 2048 + off);
      i64x2 A2 = *reinterpret_cast<const i64x2*>(Ab + abase + 4096 + off);
      i64x2 A3 = *reinterpret_cast<const i64x2*>(Ab + abase + 6144 + off);
      i64x2 B0 = *reinterpret_cast<const i64x2*>(Bb + bbase + off);
      i64x2 B1 = *reinterpret_cast<const i64x2*>(Bb + bbase + 2048 + off);
      i64x2 B2 = *reinterpret_cast<const i64x2*>(Bb + bbase + 4096 + off);
      i64x2 B3 = *reinterpret_cast<const i64x2*>(Bb + bbase + 6144 + off);
#pragma unroll
      for (int e = 0; e < 2; ++e) {
        const long a[4] = {A0[e], A1[e], A2[e], A3[e]};
        const long b[4] = {B0[e], B1[e], B2[e], B3[e]};
#pragma unroll
        for (int m = 0; m < 4; ++m)
#pragma unroll
          for (int n = 0; n < 4; ++n)
            acc[m][n] = __builtin_amdgcn_mfma_f32_16x16x32_fp8_fp8(
                a[m], b[n], acc[m][n], 0, 0, 0);
      }
    }
    __syncthreads();   // all reads of this half done before restage/alias
  }

  // ---- epilogue ph1: exp + scatter row-partials into swizzled rowmat
  // rowmat: 128 rows x 32 partial slots, byte = lrow*256 +
  //   (((slot>>2) ^ (lrow&15))<<4) + ((slot&3)<<2)   (R15-validated algebra)
  char* rowm = smem;
  float colpart[4] = {0.0f, 0.0f, 0.0f, 0.0f};
  const int slot = wc * 16 + r15;    // partial slot 0..31
#pragma unroll
  for (int m = 0; m < 4; ++m) {
#pragma unroll
    for (int v = 0; v < 4; ++v) {
      const int lrow = wr * 64 + m * 16 + (lane >> 4) * 4 + v;
      const int gi = rowBase + lrow;
      float rp = 0.0f;
#pragma unroll
      for (int n = 0; n < 4; ++n) {
        const float d = acc[m][n][v];
        float val = fast_exp2(d * E2SCALE);
        if (isdiag) {
          const int gj = colBase + wc * 64 + n * 16 + r15;
          if (gi == gj) val = 0.0f;           // exclude diagonal
        } else if (ispos) {
          const int gj = colBase + wc * 64 + n * 16 + r15;
          if (gj == gi + HALF_B) {            // positive pair
            const float pv = d * INV_T;
            pos[gi] = pv;
            pos[gj] = pv;
          }
        }
        rp += val;
        colpart[n] += val;
      }
      const int bo = (lrow << 8) + ((((slot >> 2) ^ (lrow & 15)) << 4)) +
                     ((slot & 3) << 2);
      *reinterpret_cast<float*>(rowm + bo) = rp;
    }
  }
  // column partials: reduce over hi groups -> lanes r15<16 hold 64-row sums
#pragma unroll
  for (int n = 0; n < 4; ++n) {
    float c = colpart[n];
    c += __shfl_xor(c, 16);
    c += __shfl_xor(c, 32);
    if (lane < 16) colmat[wc * 64 + n * 16 + lane][wr] = c;
  }
  __syncthreads();

  // ---- epilogue ph2: read-reduce rowmat -> P rows; colmat -> P cols
  {
    const int row = tid >> 1;          // 0..127
    const int half = tid & 1;          // 16 partials each
    f32x4 s4 = {0.0f, 0.0f, 0.0f, 0.0f};
#pragma unroll
    for (int i = 0; i < 4; ++i) {
      const int c = half * 4 + i;      // chunk 0..7
      s4 += *reinterpret_cast<const f32x4*>(
          rowm + (row << 8) + ((c ^ (row & 15)) << 4));
    }
    float s = (s4[0] + s4[1]) + (s4[2] + s4[3]);
    s += __shfl_xor(s, 1);
    if (half == 0) P[(size_t)bx * NROW + rowBase + row] = s;
  }
  if (tid < 128 && !isdiag) {
    P[(size_t)by * NROW + colBase + tid] = colmat[tid][0] + colmat[tid][1];
  }
}

// -------- kernel 3: row reduction + log + fused finalize (arrival counter) --
__global__ __launch_bounds__(256) void rowreduce_kernel(
    const float* __restrict__ P, const float* __restrict__ pos,
    float* __restrict__ lacc, unsigned int* __restrict__ counter,
    float* __restrict__ out) {
  const int i = blockIdx.x * 256 + threadIdx.x;
  float s = 0.0f;
#pragma unroll 8
  for (int k = 0; k < NB; ++k) s += P[(size_t)k * NROW + i];
  float partial = logf(s) - pos[i];
#pragma unroll
  for (int m = 32; m; m >>= 1) partial += __shfl_xor(partial, m);
  __shared__ float sred[4];
  if ((threadIdx.x & 63) == 0) sred[threadIdx.x >> 6] = partial;
  __syncthreads();
  if (threadIdx.x == 0) {
    atomicAdd(lacc, sred[0] + sred[1] + sred[2] + sred[3]);
    __threadfence();
    const unsigned done = atomicAdd(counter, 1u);
    if (done == (unsigned)(gridDim.x - 1)) {      // last block finalizes
      const float v = atomicAdd(lacc, 0.0f);      // device-coherent read
      out[0] = v * (1.0f / (float)NROW);
    }
  }
}

extern "C" void kernel_launch(void* const* d_in, const int* in_sizes, int n_in,
                              void* d_out, int out_size, void* d_ws, size_t ws_size,
                              hipStream_t stream) {
  const float* z_i = (const float*)d_in[0];
  const float* z_j = (const float*)d_in[1];
  float* out = (float*)d_out;

  char* ws = (char*)d_ws;
  unsigned char* zn = (unsigned char*)ws;                        // 2 MB fp8
  float* pos  = (float*)(ws + 2097152);                          // 32 KB
  float* P    = (float*)(ws + 2097152 + 32768);                  // 2 MB
  float* lacc = (float*)(ws + 2097152 + 32768 + 2097152);        // 4 B
  unsigned int* counter = (unsigned int*)(ws + 2097152 + 32768 + 2097152 + 4);

  normalize_kernel<<<512, 256, 0, stream>>>(z_i, z_j, zn, lacc, counter);
  gram_kernel<<<NTILES, 256, 0, stream>>>(zn, P, pos);
  rowreduce_kernel<<<NROW / 256, 256, 0, stream>>>(P, pos, lacc, counter, out);
}